// Round 2
// baseline (485.907 us; speedup 1.0000x reference)
//
#include <hip/hip_runtime.h>

#define CIN 256
#define COUT 128
#define NGRAPH 32

// ---------- f32 order-preserving map for atomicMax ----------
__device__ inline unsigned int fmap(float x) {
    unsigned int b = __float_as_uint(x);
    return (b & 0x80000000u) ? ~b : (b | 0x80000000u);
}
__device__ inline float funmap(unsigned int u) {
    unsigned int b = (u & 0x80000000u) ? (u & 0x7fffffffu) : ~u;
    return __uint_as_float(b);
}

// ---------- xw = x @ W  (f32, 256x128 tile, BK=32, 8x16 micro-tile) -------
// LDS-pipe-bound analysis: 8x16 gives 128 FMA (256 SIMD-cyc) per 6 b128
// reads -> VALUBusy ceiling ~85% vs 44% for 4x8. Per-output-element FP
// sequence still one fma per k, k ascending -> xw BIT-IDENTICAL.
// x staged as [kg][rowgrp 32][8 rows * float4 + pad] so A-reads are aligned
// b128 at 144B stride (<= 4-way, under the 8-pass floor) and staging writes
// are b128. 256 threads = 4 waves, grid 256 = 1 block/CU.
__global__ __launch_bounds__(256) void gemm_xw(const float* __restrict__ x,
                                               const float* __restrict__ W,
                                               float* __restrict__ xw) {
    __shared__ float xs4[8 * 32 * 36];   // [kg][m>>3][(m&7)*4 .. +3] pad 4/grp
    __shared__ float ws[32][132];        // [k][n]
    int t = threadIdx.x;
    int bm0 = blockIdx.x * 256;
    int tx = t & 31;          // rows tx*8 .. tx*8+7
    int ty = t >> 5;          // cols ty*16 .. ty*16+15
    float acc[8][16];
#pragma unroll
    for (int i = 0; i < 8; ++i)
#pragma unroll
        for (int j = 0; j < 16; ++j) acc[i][j] = 0.0f;

    const float* xrow = x + (size_t)(bm0 + t) * CIN;  // thread stages row t
    float* xdst = xs4 + (t >> 3) * 36 + (t & 7) * 4;  // slot of row t
    int skl = t >> 3, sn0 = (t & 7) * 16;             // W staging assignment

    for (int kc = 0; kc < 8; ++kc) {
        int k0 = kc * 32;
        // stage x tile: row t, 8 float4 (one per k-group of 4)
#pragma unroll
        for (int kg = 0; kg < 8; ++kg) {
            float4 v = *(const float4*)(xrow + k0 + kg * 4);
            *(float4*)(xdst + kg * 1152) = v;
        }
        // stage W tile (32 k x 128 n), row-major, b128 writes
        {
            const float* wp = W + (size_t)(k0 + skl) * COUT + sn0;
            float* wd = &ws[skl][sn0];
#pragma unroll
            for (int w4 = 0; w4 < 4; ++w4)
                *(float4*)(wd + 4 * w4) = *(const float4*)(wp + 4 * w4);
        }
        __syncthreads();
#pragma unroll
        for (int kg = 0; kg < 8; ++kg) {
            float va[8][4];
#pragma unroll
            for (int i = 0; i < 8; ++i)
                *(float4*)va[i] = *(const float4*)(xs4 + kg * 1152 + tx * 36 + i * 4);
#pragma unroll
            for (int kl = 0; kl < 4; ++kl) {
                int kk = kg * 4 + kl;
                float bb[16];
#pragma unroll
                for (int w4 = 0; w4 < 4; ++w4)
                    *(float4*)&bb[4 * w4] = *(const float4*)&ws[kk][ty * 16 + 4 * w4];
#pragma unroll
                for (int i = 0; i < 8; ++i) {
                    float av = va[i][kl];
#pragma unroll
                    for (int j = 0; j < 16; ++j) acc[i][j] += av * bb[j];
                }
            }
        }
        __syncthreads();
    }
#pragma unroll
    for (int i = 0; i < 8; ++i) {
        float* dp = xw + (size_t)(bm0 + tx * 8 + i) * COUT + ty * 16;
#pragma unroll
        for (int w4 = 0; w4 < 4; ++w4) {
            float4 s = {acc[i][4 * w4], acc[i][4 * w4 + 1],
                        acc[i][4 * w4 + 2], acc[i][4 * w4 + 3]};
            *(float4*)(dp + 4 * w4) = s;
        }
    }
}

// ---------- a_i = xw @ att[:C], a_j = xw @ att[C:] -------------------------
// float4 loads, but scalar FMA chain in ascending c order — BIT-IDENTICAL.
__global__ __launch_bounds__(256) void aij32_kernel(const float* __restrict__ xw,
                                                    const float* __restrict__ att,
                                                    float* __restrict__ a_i,
                                                    float* __restrict__ a_j) {
    __shared__ float sa[2 * COUT];
    int t = threadIdx.x;
    sa[t] = att[t];
    __syncthreads();
    int n = blockIdx.x * 256 + t;
    const float* row = xw + (size_t)n * COUT;
    float ai = 0.0f, aj = 0.0f;
#pragma unroll 8
    for (int c = 0; c < COUT; c += 4) {
        float4 f = *(const float4*)(row + c);
        ai += f.x * sa[c];     aj += f.x * sa[COUT + c];
        ai += f.y * sa[c + 1]; aj += f.y * sa[COUT + c + 1];
        ai += f.z * sa[c + 2]; aj += f.z * sa[COUT + c + 2];
        ai += f.w * sa[c + 3]; aj += f.w * sa[COUT + c + 3];
    }
    a_i[n] = ai;
    a_j[n] = aj;
}

// ---------- edge passes — BIT-FROZEN arithmetic ----------
__global__ void edge_max(const int* __restrict__ esrc, const int* __restrict__ edst,
                         const float* __restrict__ a_i, const float* __restrict__ a_j,
                         unsigned int* __restrict__ smax, int E, int M) {
    int e = blockIdx.x * blockDim.x + threadIdx.x;
    if (e >= M) return;
    int i, j;
    if (e < E) { j = esrc[e]; i = edst[e]; } else { i = j = e - E; }
    float l = a_i[i] + a_j[j];
    l = (l >= 0.0f) ? l : 0.2f * l;
    atomicMax(&smax[i], fmap(l));
}

__global__ void edge_exp(const int* __restrict__ esrc, const int* __restrict__ edst,
                         const float* __restrict__ a_i, const float* __restrict__ a_j,
                         const unsigned int* __restrict__ smax,
                         float* __restrict__ exb, double* __restrict__ denom,
                         int E, int M) {
    int e = blockIdx.x * blockDim.x + threadIdx.x;
    if (e >= M) return;
    int i, j;
    if (e < E) { j = esrc[e]; i = edst[e]; } else { i = j = e - E; }
    float l = a_i[i] + a_j[j];
    l = (l >= 0.0f) ? l : 0.2f * l;
    float m = funmap(smax[i]);
    float ex = expf(l - m);
    exb[e] = ex;
    atomicAdd(&denom[i], (double)ex);
}

__global__ void edge_asum(const int* __restrict__ esrc, const int* __restrict__ edst,
                          float* __restrict__ exb, const double* __restrict__ denom,
                          double* __restrict__ asum, int E, int M) {
    int e = blockIdx.x * blockDim.x + threadIdx.x;
    if (e >= M) return;
    int i, j;
    if (e < E) { j = esrc[e]; i = edst[e]; } else { i = j = e - E; }
    float al = exb[e] / (float)denom[i];
    exb[e] = al;
    atomicAdd(&asum[j], (double)al);
}

// ---------- per-graph top-k via counting rank — BIT-FROZEN comparator ------
// float4 LDS broadcasts; rank is an associative integer sum of the same
// per-element comparator -> perm EXACT-identical.
__global__ __launch_bounds__(256) void rank_kernel(const double* __restrict__ asum,
                                                   int* __restrict__ rank,
                                                   float* __restrict__ out,
                                                   int perG, int kSel,
                                                   int permOff, int tbOff) {
    __shared__ float sc[2048];
    int bpg = perG >> 8;                 // blocks per graph (8)
    int g = blockIdx.x / bpg;
    int sub = blockIdx.x - g * bpg;
    int t = threadIdx.x;
    for (int q = t; q < perG; q += 256)
        sc[q] = (float)asum[g * perG + q];
    __syncthreads();
    int m = sub * 256 + t;
    float s = sc[m];
    int r = 0;
#pragma unroll 4
    for (int q4 = 0; q4 < 2048; q4 += 4) {
        float4 f = *(const float4*)&sc[q4];
        r += (int)((f.x > s) || (f.x == s && (q4 + 0) < m));
        r += (int)((f.y > s) || (f.y == s && (q4 + 1) < m));
        r += (int)((f.z > s) || (f.z == s && (q4 + 2) < m));
        r += (int)((f.w > s) || (f.w == s && (q4 + 3) < m));
    }
    if (r < kSel) {
        int node = g * perG + m;
        int pos = g * kSel + r;
        rank[node] = pos;
        out[permOff + pos] = (float)node;
        out[tbOff + pos] = (float)g;
    }
}

// ---------- single-pass bucketed fill (replaces deg_count+scan+csr_fill) ---
__global__ void fill_bucket(const int* __restrict__ esrc, const int* __restrict__ edst,
                            const int* __restrict__ rank, const float* __restrict__ alpha,
                            int* __restrict__ cnt, int* __restrict__ bsrc,
                            float* __restrict__ balpha, int E, int M) {
    int e = blockIdx.x * blockDim.x + threadIdx.x;
    if (e >= M) return;
    int i, j;
    if (e < E) { j = esrc[e]; i = edst[e]; } else { i = j = e - E; }
    int ri = rank[i];
    if (ri < 0 || rank[j] < 0) return;
    int pos = atomicAdd(&cnt[ri], 1);
    if (pos < 64) {
        bsrc[(ri << 6) + pos] = j;
        balpha[(ri << 6) + pos] = alpha[e];
    }
}

// ---------- atomic-free aggregation: one wave(64) per output row ----------
__global__ __launch_bounds__(256) void aggr_kernel(const int* __restrict__ cnt,
                                                   const int* __restrict__ bsrc,
                                                   const float* __restrict__ balpha,
                                                   const float* __restrict__ xw,
                                                   float* __restrict__ outf, int R) {
    int wid = (int)((blockIdx.x * 256u + threadIdx.x) >> 6);
    int lane = threadIdx.x & 63;
    if (wid >= R) return;
    int n = cnt[wid];
    if (n > 64) n = 64;
    int base = wid << 6;
    float2 acc = {0.0f, 0.0f};
    for (int p = 0; p < n; ++p) {
        int j = bsrc[base + p];
        float al = balpha[base + p];
        float2 xv = *(const float2*)(xw + (size_t)j * COUT + lane * 2);
        acc.x += xv.x * al;
        acc.y += xv.y * al;
    }
    *(float2*)(outf + (size_t)wid * COUT + lane * 2) = acc;
}

// ---------- batchnorm ----------
__global__ __launch_bounds__(256) void bn_stats(const float* __restrict__ outf,
                                                double* __restrict__ acc, int R) {
    int t = threadIdx.x;
    int c = t & 127;
    int r0 = blockIdx.x * 2 + (t >> 7);
    double s = 0.0, s2 = 0.0;
    for (int r = r0; r < R; r += 512) {
        double v = (double)outf[(size_t)r * COUT + c];
        s += v; s2 += v * v;
    }
    atomicAdd(&acc[c], s);
    atomicAdd(&acc[128 + c], s2);
}

__global__ void bn_apply(float* __restrict__ outf, const double* __restrict__ acc,
                         const float* __restrict__ gamma, const float* __restrict__ beta,
                         const int* __restrict__ bnflag, int R) {
    int idx = blockIdx.x * blockDim.x + threadIdx.x;
    if (idx >= R * COUT) return;
    if (*bnflag == 0) return;
    int c = idx & 127;
    double invR = 1.0 / (double)R;
    double mu = acc[c] * invR;
    double var = acc[128 + c] * invR - mu * mu;
    double inv = 1.0 / sqrt(var + 1e-5);
    outf[idx] = (float)(((double)outf[idx] - mu) * inv * (double)gamma[c] + (double)beta[c]);
}

extern "C" void kernel_launch(void* const* d_in, const int* in_sizes, int n_in,
                              void* d_out, int out_size, void* d_ws, size_t ws_size,
                              hipStream_t stream) {
    const float* x     = (const float*)d_in[0];
    const float* W     = (const float*)d_in[1];
    const float* att   = (const float*)d_in[2];
    const float* gamma = (const float*)d_in[3];
    const float* beta  = (const float*)d_in[4];
    const int*   eidx  = (const int*)d_in[5];
    const int*   bnfl  = (const int*)d_in[7];

    const int N = in_sizes[0] / CIN;       // 65536
    const int E = in_sizes[5] / 2;         // 1048576
    const int M = E + N;                   // + self loops
    const int perG = N / NGRAPH;           // 2048
    const int kSel = perG / 2;             // 1024
    const int R = NGRAPH * kSel;           // 32768
    const int permOff = R * COUT;
    const int tbOff = permOff + R;

    const int* esrc = eidx;
    const int* edst = eidx + E;

    char* w = (char*)d_ws;
    float*  xw     = (float*)w;             w += (size_t)N * COUT * 4;
    float*  a_i    = (float*)w;             w += (size_t)N * 4;
    float*  a_j    = (float*)w;             w += (size_t)N * 4;
    unsigned int* smax = (unsigned int*)w;  w += (size_t)N * 4;
    double* denom  = (double*)w;            w += (size_t)N * 8;
    double* asum   = (double*)w;            w += (size_t)N * 8;
    float*  exb    = (float*)w;             w += (size_t)M * 4;   // becomes alpha
    int*    rank   = (int*)w;               w += (size_t)N * 4;
    int*    cnt    = (int*)w;               w += (size_t)R * 4;
    int*    bsrc   = (int*)w;               w += (size_t)R * 64 * 4;
    float*  balpha = (float*)w;             w += (size_t)R * 64 * 4;
    double* bnacc  = (double*)w;            w += 256 * 8;

    float* out = (float*)d_out;

    hipMemsetAsync(smax, 0, (size_t)N * 4, stream);
    hipMemsetAsync(denom, 0, (size_t)N * 8, stream);
    hipMemsetAsync(asum, 0, (size_t)N * 8, stream);
    hipMemsetAsync(rank, 0xFF, (size_t)N * 4, stream);
    hipMemsetAsync(cnt, 0, (size_t)R * 4, stream);
    hipMemsetAsync(bnacc, 0, 256 * 8, stream);

    gemm_xw<<<N / 256, 256, 0, stream>>>(x, W, xw);
    aij32_kernel<<<N / 256, 256, 0, stream>>>(xw, att, a_i, a_j);

    int eblocks = (M + 255) / 256;
    edge_max<<<eblocks, 256, 0, stream>>>(esrc, edst, a_i, a_j, smax, E, M);
    edge_exp<<<eblocks, 256, 0, stream>>>(esrc, edst, a_i, a_j, smax, exb, denom, E, M);
    edge_asum<<<eblocks, 256, 0, stream>>>(esrc, edst, exb, denom, asum, E, M);

    rank_kernel<<<NGRAPH * (perG >> 8), 256, 0, stream>>>(asum, rank, out,
                                                          perG, kSel, permOff, tbOff);

    fill_bucket<<<eblocks, 256, 0, stream>>>(esrc, edst, rank, exb, cnt, bsrc, balpha, E, M);

    aggr_kernel<<<(R * 64 + 255) / 256, 256, 0, stream>>>(cnt, bsrc, balpha, xw, out, R);

    bn_stats<<<256, 256, 0, stream>>>(out, bnacc, R);
    bn_apply<<<(R * COUT + 255) / 256, 256, 0, stream>>>(out, bnacc, gamma, beta, bnfl, R);
}

// Round 4
// 464.012 us; speedup vs baseline: 1.0472x; 1.0472x over previous
//
#include <hip/hip_runtime.h>

#define CIN 256
#define COUT 128
#define NGRAPH 32

// ---------- f32 order-preserving map for atomicMax ----------
__device__ inline unsigned int fmap(float x) {
    unsigned int b = __float_as_uint(x);
    return (b & 0x80000000u) ? ~b : (b | 0x80000000u);
}
__device__ inline float funmap(unsigned int u) {
    unsigned int b = (u & 0x80000000u) ? (u & 0x7fffffffu) : ~u;
    return __uint_as_float(b);
}

// ---------- xw = x @ W  (f32, 64x128 tile, BK=32, 4x8 micro-tile) ---------
// TOKEN-IDENTICAL to the round-1 kernel that passed (absmax 768, 70.4us).
// r3's restructured loop changed xw bits (perm absmax 1536 > thr) despite a
// provably-correct layout -> compiler FP reassociation. The inner loop source
// is part of the frozen interface: DO NOT restructure it.
__global__ __launch_bounds__(256) void gemm_xw(const float* __restrict__ x,
                                               const float* __restrict__ W,
                                               float* __restrict__ xw) {
    __shared__ float xs[32][68];    // [k][m]  64 rows + pad (272B row = 17*16B)
    __shared__ float ws[32][132];   // [k][n] 128 cols + pad (528B row = 33*16B)
    int t = threadIdx.x;
    int bm0 = blockIdx.x * 64;
    int tx = t & 15;     // rows 4*tx .. 4*tx+3
    int ty = t >> 4;     // cols 8*ty .. 8*ty+7
    float acc[4][8];
#pragma unroll
    for (int i = 0; i < 4; ++i)
#pragma unroll
        for (int j = 0; j < 8; ++j) acc[i][j] = 0.0f;

    for (int kc = 0; kc < CIN / 32; ++kc) {
        int k0 = kc * 32;
        {   // stage x tile (64 rows x 32 k, transposed to [k][m])
            int ml = t >> 2, kq = (t & 3) * 8;
            const float* sp = x + (size_t)(bm0 + ml) * CIN + k0 + kq;
            float4 v0 = ((const float4*)sp)[0];
            float4 v1 = ((const float4*)sp)[1];
            xs[kq + 0][ml] = v0.x;  xs[kq + 1][ml] = v0.y;
            xs[kq + 2][ml] = v0.z;  xs[kq + 3][ml] = v0.w;
            xs[kq + 4][ml] = v1.x;  xs[kq + 5][ml] = v1.y;
            xs[kq + 6][ml] = v1.z;  xs[kq + 7][ml] = v1.w;
        }
        {   // stage W tile (32 k x 128 n)
            int kl = t >> 3, n0 = (t & 7) * 16;
            const float* sp = W + (size_t)(k0 + kl) * COUT + n0;
#pragma unroll
            for (int w4 = 0; w4 < 4; ++w4)
                *(float4*)&ws[kl][n0 + 4 * w4] = *(const float4*)(sp + 4 * w4);
        }
        __syncthreads();
#pragma unroll 4
        for (int kk = 0; kk < 32; ++kk) {
            float aa[4], bb[8];
            *(float4*)&aa[0] = *(float4*)&xs[kk][tx * 4];
            *(float4*)&bb[0] = *(float4*)&ws[kk][ty * 8];
            *(float4*)&bb[4] = *(float4*)&ws[kk][ty * 8 + 4];
#pragma unroll
            for (int i = 0; i < 4; ++i)
#pragma unroll
                for (int j = 0; j < 8; ++j) acc[i][j] += aa[i] * bb[j];
        }
        __syncthreads();
    }
#pragma unroll
    for (int i = 0; i < 4; ++i) {
        float* dp = xw + (size_t)(bm0 + tx * 4 + i) * COUT + ty * 8;
        float4 s0 = {acc[i][0], acc[i][1], acc[i][2], acc[i][3]};
        float4 s1 = {acc[i][4], acc[i][5], acc[i][6], acc[i][7]};
        *(float4*)dp = s0;
        *(float4*)(dp + 4) = s1;
    }
}

// ---------- a_i = xw @ att[:C], a_j = xw @ att[C:] -------------------------
// float4 loads, but scalar FMA chain in ascending c order — BIT-IDENTICAL.
__global__ __launch_bounds__(256) void aij32_kernel(const float* __restrict__ xw,
                                                    const float* __restrict__ att,
                                                    float* __restrict__ a_i,
                                                    float* __restrict__ a_j) {
    __shared__ float sa[2 * COUT];
    int t = threadIdx.x;
    sa[t] = att[t];
    __syncthreads();
    int n = blockIdx.x * 256 + t;
    const float* row = xw + (size_t)n * COUT;
    float ai = 0.0f, aj = 0.0f;
#pragma unroll 8
    for (int c = 0; c < COUT; c += 4) {
        float4 f = *(const float4*)(row + c);
        ai += f.x * sa[c];     aj += f.x * sa[COUT + c];
        ai += f.y * sa[c + 1]; aj += f.y * sa[COUT + c + 1];
        ai += f.z * sa[c + 2]; aj += f.z * sa[COUT + c + 2];
        ai += f.w * sa[c + 3]; aj += f.w * sa[COUT + c + 3];
    }
    a_i[n] = ai;
    a_j[n] = aj;
}

// ---------- edge passes — BIT-FROZEN arithmetic ----------
__global__ void edge_max(const int* __restrict__ esrc, const int* __restrict__ edst,
                         const float* __restrict__ a_i, const float* __restrict__ a_j,
                         unsigned int* __restrict__ smax, int E, int M) {
    int e = blockIdx.x * blockDim.x + threadIdx.x;
    if (e >= M) return;
    int i, j;
    if (e < E) { j = esrc[e]; i = edst[e]; } else { i = j = e - E; }
    float l = a_i[i] + a_j[j];
    l = (l >= 0.0f) ? l : 0.2f * l;
    atomicMax(&smax[i], fmap(l));
}

__global__ void edge_exp(const int* __restrict__ esrc, const int* __restrict__ edst,
                         const float* __restrict__ a_i, const float* __restrict__ a_j,
                         const unsigned int* __restrict__ smax,
                         float* __restrict__ exb, double* __restrict__ denom,
                         int E, int M) {
    int e = blockIdx.x * blockDim.x + threadIdx.x;
    if (e >= M) return;
    int i, j;
    if (e < E) { j = esrc[e]; i = edst[e]; } else { i = j = e - E; }
    float l = a_i[i] + a_j[j];
    l = (l >= 0.0f) ? l : 0.2f * l;
    float m = funmap(smax[i]);
    float ex = expf(l - m);
    exb[e] = ex;
    atomicAdd(&denom[i], (double)ex);
}

__global__ void edge_asum(const int* __restrict__ esrc, const int* __restrict__ edst,
                          float* __restrict__ exb, const double* __restrict__ denom,
                          double* __restrict__ asum, int E, int M) {
    int e = blockIdx.x * blockDim.x + threadIdx.x;
    if (e >= M) return;
    int i, j;
    if (e < E) { j = esrc[e]; i = edst[e]; } else { i = j = e - E; }
    float al = exb[e] / (float)denom[i];
    exb[e] = al;
    atomicAdd(&asum[j], (double)al);
}

// ---------- per-graph top-k via counting rank — BIT-FROZEN comparator ------
// Also initializes rank=-1 for unselected nodes, zeroes cnt[pos] for selected
// ones, and block 0 zeroes bnacc — replaces three memset dispatches. Each
// slot is written exactly once (r is a permutation within each graph).
__global__ __launch_bounds__(256) void rank_kernel(const double* __restrict__ asum,
                                                   int* __restrict__ rank,
                                                   float* __restrict__ out,
                                                   int* __restrict__ cnt,
                                                   double* __restrict__ bnacc,
                                                   int perG, int kSel,
                                                   int permOff, int tbOff) {
    __shared__ float sc[2048];
    int bpg = perG >> 8;                 // blocks per graph (8)
    int g = blockIdx.x / bpg;
    int sub = blockIdx.x - g * bpg;
    int t = threadIdx.x;
    if (blockIdx.x == 0) bnacc[t] = 0.0;   // 256 doubles, consumed by bn_stats
    for (int q = t; q < perG; q += 256)
        sc[q] = (float)asum[g * perG + q];
    __syncthreads();
    int m = sub * 256 + t;
    float s = sc[m];
    int r = 0;
#pragma unroll 4
    for (int q4 = 0; q4 < 2048; q4 += 4) {
        float4 f = *(const float4*)&sc[q4];
        r += (int)((f.x > s) || (f.x == s && (q4 + 0) < m));
        r += (int)((f.y > s) || (f.y == s && (q4 + 1) < m));
        r += (int)((f.z > s) || (f.z == s && (q4 + 2) < m));
        r += (int)((f.w > s) || (f.w == s && (q4 + 3) < m));
    }
    int node = g * perG + m;
    if (r < kSel) {
        int pos = g * kSel + r;
        rank[node] = pos;
        cnt[pos] = 0;
        out[permOff + pos] = (float)node;
        out[tbOff + pos] = (float)g;
    } else {
        rank[node] = -1;
    }
}

// ---------- single-pass bucketed fill ----------
__global__ void fill_bucket(const int* __restrict__ esrc, const int* __restrict__ edst,
                            const int* __restrict__ rank, const float* __restrict__ alpha,
                            int* __restrict__ cnt, int* __restrict__ bsrc,
                            float* __restrict__ balpha, int E, int M) {
    int e = blockIdx.x * blockDim.x + threadIdx.x;
    if (e >= M) return;
    int i, j;
    if (e < E) { j = esrc[e]; i = edst[e]; } else { i = j = e - E; }
    int ri = rank[i];
    if (ri < 0 || rank[j] < 0) return;
    int pos = atomicAdd(&cnt[ri], 1);
    if (pos < 64) {
        bsrc[(ri << 6) + pos] = j;
        balpha[(ri << 6) + pos] = alpha[e];
    }
}

// ---------- atomic-free aggregation: one wave(64) per output row ----------
__global__ __launch_bounds__(256) void aggr_kernel(const int* __restrict__ cnt,
                                                   const int* __restrict__ bsrc,
                                                   const float* __restrict__ balpha,
                                                   const float* __restrict__ xw,
                                                   float* __restrict__ outf, int R) {
    int wid = (int)((blockIdx.x * 256u + threadIdx.x) >> 6);
    int lane = threadIdx.x & 63;
    if (wid >= R) return;
    int n = cnt[wid];
    if (n > 64) n = 64;
    int base = wid << 6;
    float2 acc = {0.0f, 0.0f};
    for (int p = 0; p < n; ++p) {
        int j = bsrc[base + p];
        float al = balpha[base + p];
        float2 xv = *(const float2*)(xw + (size_t)j * COUT + lane * 2);
        acc.x += xv.x * al;
        acc.y += xv.y * al;
    }
    *(float2*)(outf + (size_t)wid * COUT + lane * 2) = acc;
}

// ---------- batchnorm ----------
__global__ __launch_bounds__(256) void bn_stats(const float* __restrict__ outf,
                                                double* __restrict__ acc, int R) {
    int t = threadIdx.x;
    int c = t & 127;
    int r0 = blockIdx.x * 2 + (t >> 7);
    double s = 0.0, s2 = 0.0;
    for (int r = r0; r < R; r += 512) {
        double v = (double)outf[(size_t)r * COUT + c];
        s += v; s2 += v * v;
    }
    atomicAdd(&acc[c], s);
    atomicAdd(&acc[128 + c], s2);
}

__global__ void bn_apply(float* __restrict__ outf, const double* __restrict__ acc,
                         const float* __restrict__ gamma, const float* __restrict__ beta,
                         const int* __restrict__ bnflag, int R) {
    int idx = blockIdx.x * blockDim.x + threadIdx.x;
    if (idx >= R * COUT) return;
    if (*bnflag == 0) return;
    int c = idx & 127;
    double invR = 1.0 / (double)R;
    double mu = acc[c] * invR;
    double var = acc[128 + c] * invR - mu * mu;
    double inv = 1.0 / sqrt(var + 1e-5);
    outf[idx] = (float)(((double)outf[idx] - mu) * inv * (double)gamma[c] + (double)beta[c]);
}

extern "C" void kernel_launch(void* const* d_in, const int* in_sizes, int n_in,
                              void* d_out, int out_size, void* d_ws, size_t ws_size,
                              hipStream_t stream) {
    const float* x     = (const float*)d_in[0];
    const float* W     = (const float*)d_in[1];
    const float* att   = (const float*)d_in[2];
    const float* gamma = (const float*)d_in[3];
    const float* beta  = (const float*)d_in[4];
    const int*   eidx  = (const int*)d_in[5];
    const int*   bnfl  = (const int*)d_in[7];

    const int N = in_sizes[0] / CIN;       // 65536
    const int E = in_sizes[5] / 2;         // 1048576
    const int M = E + N;                   // + self loops
    const int perG = N / NGRAPH;           // 2048
    const int kSel = perG / 2;             // 1024
    const int R = NGRAPH * kSel;           // 32768
    const int permOff = R * COUT;
    const int tbOff = permOff + R;

    const int* esrc = eidx;
    const int* edst = eidx + E;

    char* w = (char*)d_ws;
    float*  xw     = (float*)w;             w += (size_t)N * COUT * 4;
    float*  a_i    = (float*)w;             w += (size_t)N * 4;
    float*  a_j    = (float*)w;             w += (size_t)N * 4;
    // --- contiguous zero-fill region: smax, denom, asum (one memset) ---
    unsigned int* smax = (unsigned int*)w;  w += (size_t)N * 4;
    double* denom  = (double*)w;            w += (size_t)N * 8;
    double* asum   = (double*)w;            w += (size_t)N * 8;
    // -------------------------------------------------------------------
    float*  exb    = (float*)w;             w += (size_t)M * 4;   // becomes alpha
    int*    rank   = (int*)w;               w += (size_t)N * 4;   // init by rank_kernel
    int*    cnt    = (int*)w;               w += (size_t)R * 4;   // init by rank_kernel
    int*    bsrc   = (int*)w;               w += (size_t)R * 64 * 4;
    float*  balpha = (float*)w;             w += (size_t)R * 64 * 4;
    double* bnacc  = (double*)w;            w += 256 * 8;         // init by rank_kernel

    float* out = (float*)d_out;

    // single fused memset over contiguous smax(4B*N) + denom(8B*N) + asum(8B*N)
    hipMemsetAsync(smax, 0, (size_t)N * (4 + 8 + 8), stream);

    gemm_xw<<<N / 64, 256, 0, stream>>>(x, W, xw);
    aij32_kernel<<<N / 256, 256, 0, stream>>>(xw, att, a_i, a_j);

    int eblocks = (M + 255) / 256;
    edge_max<<<eblocks, 256, 0, stream>>>(esrc, edst, a_i, a_j, smax, E, M);
    edge_exp<<<eblocks, 256, 0, stream>>>(esrc, edst, a_i, a_j, smax, exb, denom, E, M);
    edge_asum<<<eblocks, 256, 0, stream>>>(esrc, edst, exb, denom, asum, E, M);

    rank_kernel<<<NGRAPH * (perG >> 8), 256, 0, stream>>>(asum, rank, out, cnt, bnacc,
                                                          perG, kSel, permOff, tbOff);

    fill_bucket<<<eblocks, 256, 0, stream>>>(esrc, edst, rank, exb, cnt, bsrc, balpha, E, M);

    aggr_kernel<<<(R * 64 + 255) / 256, 256, 0, stream>>>(cnt, bsrc, balpha, xw, out, R);

    bn_stats<<<256, 256, 0, stream>>>(out, bnacc, R);
    bn_apply<<<(R * COUT + 255) / 256, 256, 0, stream>>>(out, bnacc, gamma, beta, bnfl, R);
}